// Round 14
// baseline (363.289 us; speedup 1.0000x reference)
//
#include <hip/hip_runtime.h>
#include <math.h>

#define KNN 20
#define PPTS 1024
#define NCL 16

typedef _Float16 f16x8 __attribute__((ext_vector_type(8)));
typedef _Float16 f16x4 __attribute__((ext_vector_type(4)));
typedef float f32x4 __attribute__((ext_vector_type(4)));

__device__ __forceinline__ float lrelu(float x) { return x > 0.f ? x : 0.2f * x; }

// DPP max-reduce step (ctrl must be a literal)
#define DPPMAX(x, ctrl) { \
    unsigned _t = (unsigned)__builtin_amdgcn_update_dpp((int)(x), (int)(x), ctrl, 0xF, 0xF, false); \
    (x) = (x) > _t ? (x) : _t; }

// Fragment-tiled f16 layout: 16-row x 32-col tiles, row-major within tile.
// half-index(row, k, K) = (row>>4)*16*K + (k>>5)*512 + (row&15)*32 + (k&31)

// XCD-affinity swizzle: all blocks of cluster c carry wgid%8 == (c&7).

// NUMERICS (r5/r7, fixed r8): knn key = ONE IEEE fma, fmaf(2,acc,-sqj), sqi
// dropped. Bit-deterministic under any codegen; absmax tripwire = 0.0078125.
// STRUCTURE RULES: (r9) r8's lazy top-3 extraction is the keeper. (r11/r12)
// fusions must PRESERVE PARALLEL WIDTH. r14: grampk||uv fused at exact r10
// width — 4 r10-uv-blocks (f'=4k+s) per 16-wave block; all share r=k>>1 hence
// the SAME o-tile -> one shared weight staging, 4 concurrent sub-blocks.
// NU=(O>>6)*64 uv blocks first (NU%8==0 keeps grampk XCD affinity).

// ---------------- gather: hf16 tiled (K=128) + row sq ----------------
__global__ void gather_kernel(const float4* __restrict__ feat,
                              const int* __restrict__ clusters,
                              f16x4* __restrict__ hf,
                              float* __restrict__ sqp) {
    int n = blockIdx.x * 256 + threadIdx.x;   // over NCL*PPTS*32 float4s
    int c4 = n & 31;                           // k = c4*4, K=128
    int row = n >> 5;
    int src = clusters[row];
    float4 v = feat[(size_t)src * 32 + c4];
    f16x4 o;
    o[0] = (_Float16)v.x; o[1] = (_Float16)v.y; o[2] = (_Float16)v.z; o[3] = (_Float16)v.w;
    hf[(size_t)(row >> 4) * 512 + (c4 >> 3) * 128 + (row & 15) * 8 + (c4 & 7)] = o;
    float s = v.x * v.x + v.y * v.y + v.z * v.z + v.w * v.w;
    #pragma unroll
    for (int off = 16; off; off >>= 1) s += __shfl_xor(s, off);   // 32-lane group
    if (c4 == 0) { sqp[2 * row] = s; sqp[2 * row + 1] = 0.f; }
}

// ---------------- fused prep: W5 tof16 (blocks 0..255) + 4x weight split/convert ----------------
__global__ void prep_kernel(const float* __restrict__ W5, f16x4* __restrict__ dst5,
                            const float* __restrict__ W1, f16x4* __restrict__ wn1, f16x4* __restrict__ wv1,
                            const float* __restrict__ W2, f16x4* __restrict__ wn2, f16x4* __restrict__ wv2,
                            const float* __restrict__ W3, f16x4* __restrict__ wn3, f16x4* __restrict__ wv3,
                            const float* __restrict__ W4, f16x4* __restrict__ wn4, f16x4* __restrict__ wv4) {
    int bk = blockIdx.x;
    if (bk < 256) {
        // ---- tof16 tiled (K=512) ----
        int n = bk * 256 + threadIdx.x;
        int c4 = n & 127;
        int row = n >> 7;
        float4 v = *(const float4*)&W5[(size_t)row * 512 + c4 * 4];
        f16x4 o;
        o[0] = (_Float16)v.x; o[1] = (_Float16)v.y; o[2] = (_Float16)v.z; o[3] = (_Float16)v.w;
        dst5[(size_t)(row >> 4) * 2048 + (c4 >> 3) * 128 + (row & 15) * 8 + (c4 & 7)] = o;
        return;
    }
    const float* W; f16x4* wn; f16x4* wv; int lgC4, n0;
    if (bk < 264)      { W = W1; wn = wn1; wv = wv1; lgC4 = 5; n0 = bk - 256; }  // 64x128: 8 blocks
    else if (bk < 268) { W = W2; wn = wn2; wv = wv2; lgC4 = 4; n0 = bk - 264; }  // 64x64:  4 blocks
    else if (bk < 276) { W = W3; wn = wn3; wv = wv3; lgC4 = 4; n0 = bk - 268; }  // 128x64: 8 blocks
    else               { W = W4; wn = wn4; wv = wv4; lgC4 = 5; n0 = bk - 276; }  // 256x128:32 blocks
    int n = n0 * 256 + threadIdx.x;
    int c4 = n & ((1 << lgC4) - 1);
    int o = n >> lgC4;
    int C = 4 << lgC4;
    float4 a = *(const float4*)&W[(size_t)o * 2 * C + c4 * 4];
    float4 b = *(const float4*)&W[(size_t)o * 2 * C + C + c4 * 4];
    f16x4 on, ov;
    on[0] = (_Float16)a.x; on[1] = (_Float16)a.y; on[2] = (_Float16)a.z; on[3] = (_Float16)a.w;
    ov[0] = (_Float16)(b.x - a.x); ov[1] = (_Float16)(b.y - a.y);
    ov[2] = (_Float16)(b.z - a.z); ov[3] = (_Float16)(b.w - a.w);
    size_t ti = (size_t)(o >> 4) * (C * 4) + (c4 >> 3) * 128 + (o & 15) * 8 + (c4 & 7);
    wn[ti] = on; wv[ti] = ov;
}

// ---------------- fused stage: uv (blocks < NU, r10 width) || grampk (blocks >= NU) ----------------
// uv: 16 waves = 4 CONCURRENT r10-uv-blocks f'=4k+s (s=w>>2, wsub=w&3).
// All 4 share r=f'>>3=k>>1 -> same (ox,yy) -> same weight tile: staged once.
// grampk: EXACT r8/r10 body (bit-pinned keys). Both replay r10's exact
// value-producing sequences -> U/V/idx bitwise identical.
template<int C>
__global__ __launch_bounds__(1024, 4) void stagefu_kernel(
    const _Float16* __restrict__ hf, const float* __restrict__ sqp,
    int* __restrict__ idx, int lgO, int NU,
    const _Float16* __restrict__ wn, const _Float16* __restrict__ wv,
    float* __restrict__ U, float* __restrict__ V)
{
    __shared__ char smem[65536];
    const int w = threadIdx.x >> 6;          // 0..15
    const int lane = threadIdx.x & 63;
    const int col16 = lane & 15, quad = lane >> 4;

    if ((int)blockIdx.x < NU) {
        // ================= uv: 4 concurrent r10 blocks, shared weight staging =================
        _Float16* nsh = (_Float16*)smem;              // NBLK*640 halfs
        _Float16* vsh = nsh + (4 * (C / 32)) * 640;
        const int O = 1 << lgO;
        const int k = blockIdx.x;
        const int s = w >> 2;                 // sub-block 0..3
        const int wsub = w & 3;               // r10 wave index
        const int fp = k * 4 + s;             // r10 uv block id
        const int r = fp >> 3;                // == k>>1, same for all s
        const int c = (fp & 7) + 8 * (r >> (lgO - 2));      // cluster (differs per s)
        const int i2 = r & ((1 << (lgO - 2)) - 1);
        const int ox = i2 & ((O >> 6) - 1);                 // o-tile (shared)
        const int yy = i2 >> (lgO - 6);                     // row-tile (shared)
        const int r0 = (c * 16 + yy) * 64 + wsub * 16;
        const int o0 = ox * 64;
        const _Float16* aB = hf + (size_t)(r0 >> 4) * 16 * C + col16 * 32 + quad * 8;
        const _Float16* nS = wn + (size_t)(o0 >> 4) * 16 * C;   // 64 x C halfs, linear
        const _Float16* vS = wv + (size_t)(o0 >> 4) * 16 * C;
        int tid = threadIdx.x;
        if (tid * 8 < 64 * C) {               // one pass: r10's exact (h,d) map
            int h = tid * 8;
            int blk = h >> 9, col = (h >> 5) & 15, q = (h >> 3) & 3;
            int d = blk * 640 + col * 40 + q * 8;
            *(f16x8*)&nsh[d] = *(const f16x8*)&nS[h];
            *(f16x8*)&vsh[d] = *(const f16x8*)&vS[h];
        }
        __syncthreads();
        f32x4 au[4] = {}, av[4] = {};
        #pragma unroll
        for (int kc = 0; kc < C / 32; kc++) {
            f16x8 a = *(const f16x8*)&aB[kc * 512];
            #pragma unroll
            for (int t = 0; t < 4; t++) {
                int d = (t * (C / 32) + kc) * 640 + col16 * 40 + quad * 8;
                f16x8 bn = *(const f16x8*)&nsh[d];
                au[t] = __builtin_amdgcn_mfma_f32_16x16x32_f16(a, bn, au[t], 0, 0, 0);
                f16x8 bv = *(const f16x8*)&vsh[d];
                av[t] = __builtin_amdgcn_mfma_f32_16x16x32_f16(a, bv, av[t], 0, 0, 0);
            }
        }
        #pragma unroll
        for (int t = 0; t < 4; t++) {
            int o = o0 + t * 16 + col16;
            #pragma unroll
            for (int r2 = 0; r2 < 4; r2++) {
                int p = r0 + quad * 4 + r2;
                U[((size_t)p << lgO) + o] = au[t][r2];
                V[((size_t)p << lgO) + o] = av[t][r2];
            }
        }
    } else {
        // ================= grampk (EXACT r8/r10 body) =================
        unsigned* keys = (unsigned*)smem;     // 16*1024
        const int f = (int)blockIdx.x - NU;   // NU%8==0 -> affinity kept
        const int g = f >> 3;
        const int b = (f & 7) + 8 * (g >> 6);    // cluster (XCD-affine)
        const int bxi = g & 63;                   // row-tile within cluster
        const _Float16* hb = hf + (size_t)b * PPTS * C;
        const float* sqb = sqp + 2 * (b << 10);
        const int i0 = bxi * 16;
        const int j0 = w * 64;
        const _Float16* aB = hb + (size_t)bxi * 16 * C + col16 * 32 + quad * 8;
        const _Float16* bB = hb + (size_t)(w * 4) * 16 * C + col16 * 32 + quad * 8;
        f32x4 acc[4] = {};
        #pragma unroll
        for (int kc = 0; kc < C / 32; kc++) {
            f16x8 a = *(const f16x8*)&aB[kc * 512];
            #pragma unroll
            for (int t = 0; t < 4; t++) {
                f16x8 bf = *(const f16x8*)&bB[(size_t)t * 16 * C + kc * 512];
                acc[t] = __builtin_amdgcn_mfma_f32_16x16x32_f16(a, bf, acc[t], 0, 0, 0);
            }
        }
        // key = 2*g[i][j] - |h_j|^2  (single IEEE fma -> bit-deterministic)
        #pragma unroll
        for (int t = 0; t < 4; t++) {
            int j = j0 + t * 16 + col16;
            float sqj = sqb[2 * j] + sqb[2 * j + 1];
            #pragma unroll
            for (int r = 0; r < 4; r++) {
                int row = quad * 4 + r;
                float val = __builtin_fmaf(2.f, acc[t][r], -sqj);
                unsigned u = __float_as_uint(val);
                unsigned key = (u & 0x80000000u) ? ~u : (u | 0x80000000u);
                keys[(row << 10) | ((j + 2 * row) & 1023)] = (key & 0xFFFFFC00u) | (unsigned)j;
            }
        }
        __syncthreads();
        // extraction: wave w handles row w; per-lane top-3 cache (exact)
        {
            const int row = w;
            const unsigned* krow = &keys[row << 10];
            unsigned m1 = 0u, m2 = 0u, m3 = 0u;
            #pragma unroll
            for (int s = 0; s < 16; s++) {
                unsigned x = krow[s * 64 + lane];
                unsigned h1 = x > m1 ? x : m1, l1 = x < m1 ? x : m1;   // insert
                unsigned h2 = l1 > m2 ? l1 : m2, l2 = l1 < m2 ? l1 : m2;
                unsigned h3 = l2 > m3 ? l2 : m3;
                m1 = h1; m2 = h2; m3 = h3;
            }
            unsigned myout = 0;
            for (int kk = 0; kk < KNN; kk++) {
                unsigned x = m1;
                DPPMAX(x, 0xB1);   // quad_perm(1,0,3,2)
                DPPMAX(x, 0x4E);   // quad_perm(2,3,0,1)
                DPPMAX(x, 0x141);  // row_half_mirror -> 8
                DPPMAX(x, 0x140);  // row_mirror -> 16
                DPPMAX(x, 0x142);  // row_bcast15 -> 32
                DPPMAX(x, 0x143);  // row_bcast31 -> 64 @ lane63
                unsigned gm = (unsigned)__builtin_amdgcn_readlane((int)x, 63);
                if (lane == kk) myout = gm & 1023u;
                if (m1 == gm) {                  // unique winner (keys carry index)
                    if (m2 != 0u) {
                        m1 = m2; m2 = m3; m3 = 0u;   // promote cached 2nd/3rd
                    } else {
                        unsigned n1 = 0u, n2 = 0u, n3 = 0u;
                        #pragma unroll
                        for (int s = 0; s < 16; s++) {
                            unsigned x2 = krow[s * 64 + lane];
                            x2 = x2 < gm ? x2 : 0u;     // keep only remaining
                            unsigned h1 = x2 > n1 ? x2 : n1, l1 = x2 < n1 ? x2 : n1;
                            unsigned h2 = l1 > n2 ? l1 : n2, l2 = l1 < n2 ? l1 : n2;
                            unsigned h3 = l2 > n3 ? l2 : n3;
                            n1 = h1; n2 = h2; n3 = h3;
                        }
                        m1 = n1; m2 = n2; m3 = n3;
                    }
                }
            }
            if (lane < KNN) idx[((size_t)b * PPTS + i0 + row) * KNN + lane] = (int)myout;
        }
    }
}

// ---------------- aggregate: lrelu(s*(max_k U[idx] + V) + b) -> tiled f16; XCD-affine ----------------
__global__ void agg_kernel(const float* __restrict__ U, const float* __restrict__ V,
                           const int* __restrict__ idx, int lgO,
                           const float* __restrict__ sc, const float* __restrict__ bi,
                           _Float16* __restrict__ hnext,        // tiled [rows][O], may be null
                           _Float16* __restrict__ xcf, int co,  // tiled [rows][512], col offset
                           float* __restrict__ sqp)
{
    int O = 1 << lgO;
    int f = blockIdx.x;
    int rr = f >> 3;
    int c = (f & 7) + 8 * (rr >> (lgO + 2));             // cluster
    int ii = rr & ((1 << (lgO + 2)) - 1);
    int n = (((c << (lgO + 2)) + ii) << 8) + threadIdx.x;
    int o = n & (O - 1);
    int pr = n >> lgO;           // b*P+p
    int b = pr >> 10;
    const int* id = idx + (size_t)pr * KNN;
    float m = -INFINITY;
    #pragma unroll
    for (int k = 0; k < KNN; k++) {
        int j = id[k];
        float u = U[((size_t)(b * PPTS + j) << lgO) + o];
        m = fmaxf(m, u);
    }
    float val = lrelu((m + V[((size_t)pr << lgO) + o]) * sc[o] + bi[o]);
    _Float16 hv = (_Float16)val;
    int prg = pr >> 4, prr = pr & 15;
    xcf[(size_t)prg * 8192 + ((co + o) >> 5) * 512 + prr * 32 + (o & 31)] = hv;
    if (hnext) {
        hnext[(size_t)prg * 16 * O + (o >> 5) * 512 + prr * 32 + (o & 31)] = hv;
        float s = val * val;
        #pragma unroll
        for (int off = 32; off; off >>= 1) s += __shfl_xor(s, off);   // wave = 64 o's of this pr
        if ((threadIdx.x & 63) == 0) {
            sqp[2 * pr + ((o >> 6) & 1)] = s;
            if (lgO == 6) sqp[2 * pr + 1] = 0.f;
        }
    }
}

// ---------------- fused conv5 + pool: LDS-staged shared B, double-buffered ----------------
__global__ __launch_bounds__(256, 4) void conv5pool_kernel(
    const _Float16* __restrict__ xcf, const _Float16* __restrict__ w5f,
    const float* __restrict__ s5, const float* __restrict__ b5,
    float* __restrict__ pmax, float* __restrict__ psum)
{
    __shared__ _Float16 bsh[2][8 * 640];      // 2 x 10 KB
    __shared__ float lmax[4][128], lsum[4][128];
    const int f = blockIdx.x;                 // 512 blocks
    const int r = f >> 3;                     // 0..63
    const int c = (f & 7) + 8 * (r >> 5);     // cluster
    const int within = r & 31;
    const int pb = within >> 2;               // 0..7 (128-pt chunk)
    const int ob = within & 3;                // 0..3 (128-o tile)
    const int w = threadIdx.x >> 6;
    const int lane = threadIdx.x & 63;
    const int col16 = lane & 15, quad = lane >> 4;
    const int p0 = (c * 8 + pb) * 128 + w * 32;
    const int o0 = ob * 128;
    const _Float16* aB = xcf + (size_t)(p0 >> 4) * 8192 + col16 * 32 + quad * 8;
    const _Float16* bS = w5f + (size_t)(o0 >> 4) * 8192;

    // staging map: thread covers 2 x 16B; h = (s*256+tid)*8 halfs of the 8 KB chunk
    auto stage = [&](int kc, int buf) {
        #pragma unroll
        for (int s = 0; s < 2; s++) {
            int h = (s * 256 + (int)threadIdx.x) * 8;
            int t = h >> 9, rr2 = (h >> 5) & 15, q = (h >> 3) & 3;
            f16x8 x = *(const f16x8*)&bS[(size_t)t * 8192 + kc * 512 + rr2 * 32 + q * 8];
            *(f16x8*)&bsh[buf][t * 640 + rr2 * 40 + q * 8] = x;
        }
    };

    stage(0, 0);
    f32x4 acc[2][8] = {};
    for (int kc = 0; kc < 16; kc++) {
        int cur = kc & 1;
        __syncthreads();                       // bsh[cur] writes complete
        if (kc < 15) stage(kc + 1, cur ^ 1);   // prefetch next chunk
        f16x8 a0 = *(const f16x8*)&aB[kc * 512];
        f16x8 a1 = *(const f16x8*)&aB[8192 + kc * 512];
        #pragma unroll
        for (int t = 0; t < 8; t++) {
            f16x8 bf = *(const f16x8*)&bsh[cur][t * 640 + col16 * 40 + quad * 8];
            acc[0][t] = __builtin_amdgcn_mfma_f32_16x16x32_f16(a0, bf, acc[0][t], 0, 0, 0);
            acc[1][t] = __builtin_amdgcn_mfma_f32_16x16x32_f16(a1, bf, acc[1][t], 0, 0, 0);
        }
    }
    #pragma unroll
    for (int t = 0; t < 8; t++) {
        int o = o0 + t * 16 + col16;
        float sc = s5[o], bi = b5[o];
        float vm = -INFINITY, vs = 0.f;
        #pragma unroll
        for (int u = 0; u < 2; u++)
            #pragma unroll
            for (int r2 = 0; r2 < 4; r2++) {
                float val = lrelu(acc[u][t][r2] * sc + bi);
                vm = fmaxf(vm, val); vs += val;
            }
        #pragma unroll
        for (int off = 16; off < 64; off <<= 1) {
            vm = fmaxf(vm, __shfl_xor(vm, off));
            vs += __shfl_xor(vs, off);
        }
        if (quad == 0) { lmax[w][t * 16 + col16] = vm; lsum[w][t * 16 + col16] = vs; }
    }
    __syncthreads();
    if (threadIdx.x < 128) {
        int col = threadIdx.x;
        float m = lmax[0][col], s = lsum[0][col];
        #pragma unroll
        for (int q = 1; q < 4; q++) { m = fmaxf(m, lmax[q][col]); s += lsum[q][col]; }
        size_t o = (size_t)(c * 8 + pb) * 512 + o0 + col;
        pmax[o] = m; psum[o] = s;
    }
}

// ---------------- pool reduce over 8 chunks ----------------
__global__ void poolred_kernel(const float* __restrict__ pmax, const float* __restrict__ psum,
                               float* __restrict__ feat) {
    int n = blockIdx.x * 256 + threadIdx.x;   // 16*512
    int o = n & 511, cl = n >> 9;
    float m = -INFINITY, s = 0.f;
    #pragma unroll
    for (int c = 0; c < 8; c++) {
        size_t q = (size_t)(cl * 8 + c) * 512 + o;
        m = fmaxf(m, pmax[q]); s += psum[q];
    }
    feat[(size_t)cl * 1024 + o] = m;
    feat[(size_t)cl * 1024 + 512 + o] = s * (1.f / 1024.f);
}

// ---------------- final MLP: wave-per-output ----------------
__global__ void mlp1_kernel(const float* __restrict__ feat, const float* __restrict__ L1,
                            const float* __restrict__ s6, const float* __restrict__ b6,
                            float* __restrict__ z1) {
    int wid = (blockIdx.x * 256 + threadIdx.x) >> 6;   // 0..8191
    int lane = threadIdx.x & 63;
    int o = wid & 511, b = wid >> 9;
    const float* f = feat + (size_t)b * 1024;
    const float* w = L1 + (size_t)o * 1024;
    float acc = 0.f;
    #pragma unroll
    for (int i = 0; i < 16; i++) acc = fmaf(f[i * 64 + lane], w[i * 64 + lane], acc);
    #pragma unroll
    for (int off = 32; off; off >>= 1) acc += __shfl_xor(acc, off);
    if (lane == 0) z1[wid] = lrelu(acc * s6[o] + b6[o]);
}

__global__ void mlp2_kernel(const float* __restrict__ z1, const float* __restrict__ L2,
                            const float* __restrict__ bl2,
                            const float* __restrict__ s7, const float* __restrict__ b7,
                            float* __restrict__ z2) {
    int wid = (blockIdx.x * 256 + threadIdx.x) >> 6;   // 0..4095
    int lane = threadIdx.x & 63;
    int o = wid & 255, b = wid >> 8;
    const float* f = z1 + (size_t)b * 512;
    const float* w = L2 + (size_t)o * 512;
    float acc = 0.f;
    #pragma unroll
    for (int i = 0; i < 8; i++) acc = fmaf(f[i * 64 + lane], w[i * 64 + lane], acc);
    #pragma unroll
    for (int off = 32; off; off >>= 1) acc += __shfl_xor(acc, off);
    if (lane == 0) z2[wid] = lrelu((acc + bl2[o]) * s7[o] + b7[o]);
}

__global__ void mlp3_kernel(const float* __restrict__ z2, const float* __restrict__ L3,
                            const float* __restrict__ bl3, float* __restrict__ out) {
    __shared__ float red[256];
    int t = threadIdx.x;
    int b = t >> 4, q = t & 15;
    float acc = 0.f;
    for (int c = q * 16; c < q * 16 + 16; c++) acc = fmaf(z2[(size_t)b * 256 + c], L3[c], acc);
    red[t] = acc;
    __syncthreads();
    if (q == 0) {
        float s = 0.f;
        #pragma unroll
        for (int i = 0; i < 16; i++) s += red[b * 16 + i];
        s += bl3[0];
        out[b] = 1.f / (1.f + expf(-s));
    }
}

extern "C" void kernel_launch(void* const* d_in, const int* in_sizes, int n_in,
                              void* d_out, int out_size, void* d_ws, size_t ws_size,
                              hipStream_t stream) {
    const float* features = (const float*)d_in[0];
    const int*   clusters = (const int*)d_in[1];
    const float* W1 = (const float*)d_in[2];
    const float* s1 = (const float*)d_in[3];
    const float* b1 = (const float*)d_in[4];
    const float* W2 = (const float*)d_in[5];
    const float* s2 = (const float*)d_in[6];
    const float* b2 = (const float*)d_in[7];
    const float* W3 = (const float*)d_in[8];
    const float* s3 = (const float*)d_in[9];
    const float* b3 = (const float*)d_in[10];
    const float* W4 = (const float*)d_in[11];
    const float* s4 = (const float*)d_in[12];
    const float* b4 = (const float*)d_in[13];
    const float* W5 = (const float*)d_in[14];
    const float* s5 = (const float*)d_in[15];
    const float* b5 = (const float*)d_in[16];
    const float* L1 = (const float*)d_in[17];
    const float* s6 = (const float*)d_in[18];
    const float* b6 = (const float*)d_in[19];
    const float* L2 = (const float*)d_in[20];
    const float* bl2 = (const float*)d_in[21];
    const float* s7 = (const float*)d_in[22];
    const float* b7 = (const float*)d_in[23];
    const float* L3 = (const float*)d_in[24];
    const float* bl3 = (const float*)d_in[25];

    float* ws = (float*)d_ws;
    float* U   = ws;                                      // 4,194,304 floats (max O=256)
    float* V   = U + 4194304;                             // 4,194,304
    _Float16* xcf16 = (_Float16*)(V + 4194304);           // 8,388,608 halfs (tiled K=512)
    _Float16* w5f16 = xcf16 + 8388608;                    // 262,144 halfs (tiled K=512)
    _Float16* hf16  = w5f16 + 262144;                     // 2,097,152 halfs (tiled, K=C)
    _Float16* wnA   = hf16 + 2097152;                     // 4 x 32,768 halfs
    _Float16* wvA   = wnA + 131072;                       // 4 x 32,768 halfs
    int*   idx  = (int*)(wvA + 131072);                   // 327,680 ints
    float* sqp  = (float*)(idx + 327680);                 // 32,768 (2 partials/row)
    float* pmax = sqp + 32768;                            // 131,072 (65,536 used)
    float* psum = pmax + 131072;                          // 131,072 (65,536 used)
    float* feat = psum + 131072;                          // 16,384
    float* z1   = feat + 16384;                           // 8,192
    float* z2   = z1 + 8192;                              // 4,096

    _Float16* wn[4] = { wnA, wnA + 32768, wnA + 65536, wnA + 98304 };
    _Float16* wv[4] = { wvA, wvA + 32768, wvA + 65536, wvA + 98304 };

    gather_kernel<<<2048, 256, 0, stream>>>((const float4*)features, clusters,
                                            (f16x4*)hf16, sqp);
    prep_kernel<<<308, 256, 0, stream>>>(W5, (f16x4*)w5f16,
                                         W1, (f16x4*)wn[0], (f16x4*)wv[0],
                                         W2, (f16x4*)wn[1], (f16x4*)wv[1],
                                         W3, (f16x4*)wn[2], (f16x4*)wv[2],
                                         W4, (f16x4*)wn[3], (f16x4*)wv[3]);

    auto stage = [&](int si, int C, int O, int lgO,
                     const float* sc, const float* bi,
                     int co, _Float16* hnext) {
        int NU = (O >> 6) * 64;                // uv blocks first; NU % 8 == 0
        if (C == 128)
            stagefu_kernel<128><<<NU + 1024, 1024, 0, stream>>>(hf16, sqp, idx, lgO, NU,
                                                                wn[si], wv[si], U, V);
        else
            stagefu_kernel<64><<<NU + 1024, 1024, 0, stream>>>(hf16, sqp, idx, lgO, NU,
                                                               wn[si], wv[si], U, V);
        agg_kernel<<<(NCL * PPTS * O) / 256, 256, 0, stream>>>(U, V, idx, lgO, sc, bi,
                                                               hnext, xcf16, co, sqp);
    };

    stage(0, 128,  64, 6, s1, b1, 0,   hf16);
    stage(1,  64,  64, 6, s2, b2, 64,  hf16);
    stage(2,  64, 128, 7, s3, b3, 128, hf16);
    stage(3, 128, 256, 8, s4, b4, 256, (_Float16*)nullptr);

    conv5pool_kernel<<<512, 256, 0, stream>>>(xcf16, w5f16, s5, b5, pmax, psum);
    poolred_kernel<<<32, 256, 0, stream>>>(pmax, psum, feat);
    mlp1_kernel<<<2048, 256, 0, stream>>>(feat, L1, s6, b6, z1);
    mlp2_kernel<<<1024, 256, 0, stream>>>(z1, L2, bl2, s7, b7, z2);
    mlp3_kernel<<<1, 256, 0, stream>>>(z2, L3, bl3, (float*)d_out);
}

// Round 15
// 340.771 us; speedup vs baseline: 1.0661x; 1.0661x over previous
//
#include <hip/hip_runtime.h>
#include <math.h>

#define KNN 20
#define PPTS 1024
#define NCL 16

typedef _Float16 f16x8 __attribute__((ext_vector_type(8)));
typedef _Float16 f16x4 __attribute__((ext_vector_type(4)));
typedef float f32x4 __attribute__((ext_vector_type(4)));

__device__ __forceinline__ float lrelu(float x) { return x > 0.f ? x : 0.2f * x; }

// DPP max-reduce step (ctrl must be a literal)
#define DPPMAX(x, ctrl) { \
    unsigned _t = (unsigned)__builtin_amdgcn_update_dpp((int)(x), (int)(x), ctrl, 0xF, 0xF, false); \
    (x) = (x) > _t ? (x) : _t; }

// Fragment-tiled f16 layout: 16-row x 32-col tiles, row-major within tile.
// half-index(row, k, K) = (row>>4)*16*K + (k>>5)*512 + (row&15)*32 + (k&31)

// XCD-affinity swizzle: all blocks of cluster c carry wgid%8 == (c&7).

// NUMERICS (r5/r7, fixed r8): knn key = ONE IEEE fma, fmaf(2,acc,-sqj), sqi
// dropped. Bit-deterministic under any codegen; absmax tripwire = 0.0078125.
// STRUCTURE RULES (final): (r9) r8's lazy top-3 extraction is the keeper.
// (r11/r12/r14) ALL fusion variants regress — heterogeneous blocks couple
// occupancy/LDS/barrier scope; separate small kernels win on this workload.
// r15 = r13 byte-identical (best verified: 341.3 us).

// ---------------- gather: hf16 tiled (K=128) + row sq ----------------
__global__ void gather_kernel(const float4* __restrict__ feat,
                              const int* __restrict__ clusters,
                              f16x4* __restrict__ hf,
                              float* __restrict__ sqp) {
    int n = blockIdx.x * 256 + threadIdx.x;   // over NCL*PPTS*32 float4s
    int c4 = n & 31;                           // k = c4*4, K=128
    int row = n >> 5;
    int src = clusters[row];
    float4 v = feat[(size_t)src * 32 + c4];
    f16x4 o;
    o[0] = (_Float16)v.x; o[1] = (_Float16)v.y; o[2] = (_Float16)v.z; o[3] = (_Float16)v.w;
    hf[(size_t)(row >> 4) * 512 + (c4 >> 3) * 128 + (row & 15) * 8 + (c4 & 7)] = o;
    float s = v.x * v.x + v.y * v.y + v.z * v.z + v.w * v.w;
    #pragma unroll
    for (int off = 16; off; off >>= 1) s += __shfl_xor(s, off);   // 32-lane group
    if (c4 == 0) { sqp[2 * row] = s; sqp[2 * row + 1] = 0.f; }
}

// ---------------- fused prep: W5 tof16 (blocks 0..255) + 4x weight split/convert ----------------
__global__ void prep_kernel(const float* __restrict__ W5, f16x4* __restrict__ dst5,
                            const float* __restrict__ W1, f16x4* __restrict__ wn1, f16x4* __restrict__ wv1,
                            const float* __restrict__ W2, f16x4* __restrict__ wn2, f16x4* __restrict__ wv2,
                            const float* __restrict__ W3, f16x4* __restrict__ wn3, f16x4* __restrict__ wv3,
                            const float* __restrict__ W4, f16x4* __restrict__ wn4, f16x4* __restrict__ wv4) {
    int bk = blockIdx.x;
    if (bk < 256) {
        // ---- tof16 tiled (K=512) ----
        int n = bk * 256 + threadIdx.x;
        int c4 = n & 127;
        int row = n >> 7;
        float4 v = *(const float4*)&W5[(size_t)row * 512 + c4 * 4];
        f16x4 o;
        o[0] = (_Float16)v.x; o[1] = (_Float16)v.y; o[2] = (_Float16)v.z; o[3] = (_Float16)v.w;
        dst5[(size_t)(row >> 4) * 2048 + (c4 >> 3) * 128 + (row & 15) * 8 + (c4 & 7)] = o;
        return;
    }
    const float* W; f16x4* wn; f16x4* wv; int lgC4, n0;
    if (bk < 264)      { W = W1; wn = wn1; wv = wv1; lgC4 = 5; n0 = bk - 256; }  // 64x128: 8 blocks
    else if (bk < 268) { W = W2; wn = wn2; wv = wv2; lgC4 = 4; n0 = bk - 264; }  // 64x64:  4 blocks
    else if (bk < 276) { W = W3; wn = wn3; wv = wv3; lgC4 = 4; n0 = bk - 268; }  // 128x64: 8 blocks
    else               { W = W4; wn = wn4; wv = wv4; lgC4 = 5; n0 = bk - 276; }  // 256x128:32 blocks
    int n = n0 * 256 + threadIdx.x;
    int c4 = n & ((1 << lgC4) - 1);
    int o = n >> lgC4;
    int C = 4 << lgC4;
    float4 a = *(const float4*)&W[(size_t)o * 2 * C + c4 * 4];
    float4 b = *(const float4*)&W[(size_t)o * 2 * C + C + c4 * 4];
    f16x4 on, ov;
    on[0] = (_Float16)a.x; on[1] = (_Float16)a.y; on[2] = (_Float16)a.z; on[3] = (_Float16)a.w;
    ov[0] = (_Float16)(b.x - a.x); ov[1] = (_Float16)(b.y - a.y);
    ov[2] = (_Float16)(b.z - a.z); ov[3] = (_Float16)(b.w - a.w);
    size_t ti = (size_t)(o >> 4) * (C * 4) + (c4 >> 3) * 128 + (o & 15) * 8 + (c4 & 7);
    wn[ti] = on; wv[ti] = ov;
}

// ---------------- fused gram + top-K, 1024-thread blocks, tiled hf ----------------
// == EXACT r8/r10 SOURCE — bit-pinned keys ==
template<int C>
__global__ __launch_bounds__(1024, 8) void grampk_kernel(
    const _Float16* __restrict__ hf,
    const float* __restrict__ sqp, int* __restrict__ idx)
{
    __shared__ unsigned keys[16 * 1024];   // 64 KB
    const int f = blockIdx.x;
    const int g = f >> 3;
    const int b = (f & 7) + 8 * (g >> 6);    // cluster (XCD-affine)
    const int bxi = g & 63;                   // row-tile within cluster
    const _Float16* hb = hf + (size_t)b * PPTS * C;
    const float* sqb = sqp + 2 * (b << 10);
    const int w = threadIdx.x >> 6;          // 0..15
    const int lane = threadIdx.x & 63;
    const int col16 = lane & 15, quad = lane >> 4;
    const int i0 = bxi * 16;
    const int j0 = w * 64;
    const _Float16* aB = hb + (size_t)bxi * 16 * C + col16 * 32 + quad * 8;
    const _Float16* bB = hb + (size_t)(w * 4) * 16 * C + col16 * 32 + quad * 8;
    f32x4 acc[4] = {};
    #pragma unroll
    for (int kc = 0; kc < C / 32; kc++) {
        f16x8 a = *(const f16x8*)&aB[kc * 512];
        #pragma unroll
        for (int t = 0; t < 4; t++) {
            f16x8 bf = *(const f16x8*)&bB[(size_t)t * 16 * C + kc * 512];
            acc[t] = __builtin_amdgcn_mfma_f32_16x16x32_f16(a, bf, acc[t], 0, 0, 0);
        }
    }
    // key = 2*g[i][j] - |h_j|^2  (sqi dropped: constant per row i -> same top-k)
    #pragma unroll
    for (int t = 0; t < 4; t++) {
        int j = j0 + t * 16 + col16;
        float sqj = sqb[2 * j] + sqb[2 * j + 1];
        #pragma unroll
        for (int r = 0; r < 4; r++) {
            int row = quad * 4 + r;
            float val = __builtin_fmaf(2.f, acc[t][r], -sqj);   // single IEEE fma
            unsigned u = __float_as_uint(val);
            unsigned key = (u & 0x80000000u) ? ~u : (u | 0x80000000u);
            keys[(row << 10) | ((j + 2 * row) & 1023)] = (key & 0xFFFFFC00u) | (unsigned)j;
        }
    }
    __syncthreads();
    // extraction: wave w handles row w; keys stay in LDS; per-lane top-3 cache
    {
        const int row = w;
        const unsigned* krow = &keys[row << 10];
        unsigned m1 = 0u, m2 = 0u, m3 = 0u;
        #pragma unroll
        for (int s = 0; s < 16; s++) {
            unsigned x = krow[s * 64 + lane];
            unsigned h1 = x > m1 ? x : m1, l1 = x < m1 ? x : m1;   // insert
            unsigned h2 = l1 > m2 ? l1 : m2, l2 = l1 < m2 ? l1 : m2;
            unsigned h3 = l2 > m3 ? l2 : m3;
            m1 = h1; m2 = h2; m3 = h3;
        }
        unsigned myout = 0;
        for (int kk = 0; kk < KNN; kk++) {
            unsigned x = m1;
            DPPMAX(x, 0xB1);   // quad_perm(1,0,3,2)
            DPPMAX(x, 0x4E);   // quad_perm(2,3,0,1)
            DPPMAX(x, 0x141);  // row_half_mirror -> 8
            DPPMAX(x, 0x140);  // row_mirror -> 16
            DPPMAX(x, 0x142);  // row_bcast15 -> 32
            DPPMAX(x, 0x143);  // row_bcast31 -> 64 @ lane63
            unsigned gm = (unsigned)__builtin_amdgcn_readlane((int)x, 63);
            if (lane == kk) myout = gm & 1023u;
            if (m1 == gm) {                  // unique winner (keys carry index bits)
                if (m2 != 0u) {
                    m1 = m2; m2 = m3; m3 = 0u;   // promote cached 2nd/3rd
                } else {
                    unsigned n1 = 0u, n2 = 0u, n3 = 0u;
                    #pragma unroll
                    for (int s = 0; s < 16; s++) {
                        unsigned x2 = krow[s * 64 + lane];
                        x2 = x2 < gm ? x2 : 0u;     // keep only remaining values
                        unsigned h1 = x2 > n1 ? x2 : n1, l1 = x2 < n1 ? x2 : n1;
                        unsigned h2 = l1 > n2 ? l1 : n2, l2 = l1 < n2 ? l1 : n2;
                        unsigned h3 = l2 > n3 ? l2 : n3;
                        n1 = h1; n2 = h2; n3 = h3;
                    }
                    m1 = n1; m2 = n2; m3 = n3;
                }
            }
        }
        if (lane < KNN) idx[((size_t)b * PPTS + i0 + row) * KNN + lane] = (int)myout;
    }
}

// ---------------- U/V via f16 MFMA: LDS-staged shared weights, XCD-affine ----------------
// == EXACT r10 SOURCE (per-stage wn/wv buffers) ==
template<int C>
__global__ __launch_bounds__(256, 4) void uv_mfma_kernel(
    const _Float16* __restrict__ hf, int lgO,
    const _Float16* __restrict__ wn, const _Float16* __restrict__ wv,
    float* __restrict__ U, float* __restrict__ V)
{
    constexpr int NBLK = 4 * (C / 32);            // (t,kc) 512-half blocks
    __shared__ _Float16 nsh[NBLK * 640];          // 640 = 16 rows x 40-half pitch
    __shared__ _Float16 vsh[NBLK * 640];
    const int O = 1 << lgO;
    const int f = blockIdx.x;
    const int r = f >> 3;
    const int c = (f & 7) + 8 * (r >> (lgO - 2));       // cluster
    const int i2 = r & ((1 << (lgO - 2)) - 1);
    const int ox = i2 & ((O >> 6) - 1);                 // o-tile
    const int yy = i2 >> (lgO - 6);                     // row-tile within cluster
    const int w = threadIdx.x >> 6;
    const int lane = threadIdx.x & 63;
    const int col16 = lane & 15, quad = lane >> 4;
    const int r0 = (c * 16 + yy) * 64 + w * 16;
    const int o0 = ox * 64;
    const _Float16* aB = hf + (size_t)(r0 >> 4) * 16 * C + col16 * 32 + quad * 8;
    const _Float16* nS = wn + (size_t)(o0 >> 4) * 16 * C;   // 64 x C halfs, linear
    const _Float16* vS = wv + (size_t)(o0 >> 4) * 16 * C;

    // stage: 64*C halfs per matrix; thread covers 8 halfs per pass, C/32 passes
    #pragma unroll
    for (int p = 0; p < C / 32; p++) {
        int h = (p * 256 + (int)threadIdx.x) * 8;       // linear half offset
        int blk = h >> 9, col = (h >> 5) & 15, q = (h >> 3) & 3;
        int d = blk * 640 + col * 40 + q * 8;           // padded LDS offset (16B-aligned)
        *(f16x8*)&nsh[d] = *(const f16x8*)&nS[h];
        *(f16x8*)&vsh[d] = *(const f16x8*)&vS[h];
    }
    __syncthreads();

    f32x4 au[4] = {}, av[4] = {};
    #pragma unroll
    for (int kc = 0; kc < C / 32; kc++) {
        f16x8 a = *(const f16x8*)&aB[kc * 512];
        #pragma unroll
        for (int t = 0; t < 4; t++) {
            int d = (t * (C / 32) + kc) * 640 + col16 * 40 + quad * 8;
            f16x8 bn = *(const f16x8*)&nsh[d];
            au[t] = __builtin_amdgcn_mfma_f32_16x16x32_f16(a, bn, au[t], 0, 0, 0);
            f16x8 bv = *(const f16x8*)&vsh[d];
            av[t] = __builtin_amdgcn_mfma_f32_16x16x32_f16(a, bv, av[t], 0, 0, 0);
        }
    }
    #pragma unroll
    for (int t = 0; t < 4; t++) {
        int o = o0 + t * 16 + col16;
        #pragma unroll
        for (int r2 = 0; r2 < 4; r2++) {
            int p = r0 + quad * 4 + r2;
            U[((size_t)p << lgO) + o] = au[t][r2];
            V[((size_t)p << lgO) + o] = av[t][r2];
        }
    }
}

// ---------------- aggregate: lrelu(s*(max_k U[idx] + V) + b) -> tiled f16; XCD-affine ----------------
__global__ void agg_kernel(const float* __restrict__ U, const float* __restrict__ V,
                           const int* __restrict__ idx, int lgO,
                           const float* __restrict__ sc, const float* __restrict__ bi,
                           _Float16* __restrict__ hnext,        // tiled [rows][O], may be null
                           _Float16* __restrict__ xcf, int co,  // tiled [rows][512], col offset
                           float* __restrict__ sqp)
{
    int O = 1 << lgO;
    int f = blockIdx.x;
    int rr = f >> 3;
    int c = (f & 7) + 8 * (rr >> (lgO + 2));             // cluster
    int ii = rr & ((1 << (lgO + 2)) - 1);
    int n = (((c << (lgO + 2)) + ii) << 8) + threadIdx.x;
    int o = n & (O - 1);
    int pr = n >> lgO;           // b*P+p
    int b = pr >> 10;
    const int* id = idx + (size_t)pr * KNN;
    float m = -INFINITY;
    #pragma unroll
    for (int k = 0; k < KNN; k++) {
        int j = id[k];
        float u = U[((size_t)(b * PPTS + j) << lgO) + o];
        m = fmaxf(m, u);
    }
    float val = lrelu((m + V[((size_t)pr << lgO) + o]) * sc[o] + bi[o]);
    _Float16 hv = (_Float16)val;
    int prg = pr >> 4, prr = pr & 15;
    xcf[(size_t)prg * 8192 + ((co + o) >> 5) * 512 + prr * 32 + (o & 31)] = hv;
    if (hnext) {
        hnext[(size_t)prg * 16 * O + (o >> 5) * 512 + prr * 32 + (o & 31)] = hv;
        float s = val * val;
        #pragma unroll
        for (int off = 32; off; off >>= 1) s += __shfl_xor(s, off);   // wave = 64 o's of this pr
        if ((threadIdx.x & 63) == 0) {
            sqp[2 * pr + ((o >> 6) & 1)] = s;
            if (lgO == 6) sqp[2 * pr + 1] = 0.f;
        }
    }
}

// ---------------- fused conv5 + pool: LDS-staged shared B, double-buffered ----------------
__global__ __launch_bounds__(256, 4) void conv5pool_kernel(
    const _Float16* __restrict__ xcf, const _Float16* __restrict__ w5f,
    const float* __restrict__ s5, const float* __restrict__ b5,
    float* __restrict__ pmax, float* __restrict__ psum)
{
    __shared__ _Float16 bsh[2][8 * 640];      // 2 x 10 KB
    __shared__ float lmax[4][128], lsum[4][128];
    const int f = blockIdx.x;                 // 512 blocks
    const int r = f >> 3;                     // 0..63
    const int c = (f & 7) + 8 * (r >> 5);     // cluster
    const int within = r & 31;
    const int pb = within >> 2;               // 0..7 (128-pt chunk)
    const int ob = within & 3;                // 0..3 (128-o tile)
    const int w = threadIdx.x >> 6;
    const int lane = threadIdx.x & 63;
    const int col16 = lane & 15, quad = lane >> 4;
    const int p0 = (c * 8 + pb) * 128 + w * 32;
    const int o0 = ob * 128;
    const _Float16* aB = xcf + (size_t)(p0 >> 4) * 8192 + col16 * 32 + quad * 8;
    const _Float16* bS = w5f + (size_t)(o0 >> 4) * 8192;

    // staging map: thread covers 2 x 16B; h = (s*256+tid)*8 halfs of the 8 KB chunk
    auto stage = [&](int kc, int buf) {
        #pragma unroll
        for (int s = 0; s < 2; s++) {
            int h = (s * 256 + (int)threadIdx.x) * 8;
            int t = h >> 9, rr2 = (h >> 5) & 15, q = (h >> 3) & 3;
            f16x8 x = *(const f16x8*)&bS[(size_t)t * 8192 + kc * 512 + rr2 * 32 + q * 8];
            *(f16x8*)&bsh[buf][t * 640 + rr2 * 40 + q * 8] = x;
        }
    };

    stage(0, 0);
    f32x4 acc[2][8] = {};
    for (int kc = 0; kc < 16; kc++) {
        int cur = kc & 1;
        __syncthreads();                       // bsh[cur] writes complete
        if (kc < 15) stage(kc + 1, cur ^ 1);   // prefetch next chunk
        f16x8 a0 = *(const f16x8*)&aB[kc * 512];
        f16x8 a1 = *(const f16x8*)&aB[8192 + kc * 512];
        #pragma unroll
        for (int t = 0; t < 8; t++) {
            f16x8 bf = *(const f16x8*)&bsh[cur][t * 640 + col16 * 40 + quad * 8];
            acc[0][t] = __builtin_amdgcn_mfma_f32_16x16x32_f16(a0, bf, acc[0][t], 0, 0, 0);
            acc[1][t] = __builtin_amdgcn_mfma_f32_16x16x32_f16(a1, bf, acc[1][t], 0, 0, 0);
        }
    }
    #pragma unroll
    for (int t = 0; t < 8; t++) {
        int o = o0 + t * 16 + col16;
        float sc = s5[o], bi = b5[o];
        float vm = -INFINITY, vs = 0.f;
        #pragma unroll
        for (int u = 0; u < 2; u++)
            #pragma unroll
            for (int r2 = 0; r2 < 4; r2++) {
                float val = lrelu(acc[u][t][r2] * sc + bi);
                vm = fmaxf(vm, val); vs += val;
            }
        #pragma unroll
        for (int off = 16; off < 64; off <<= 1) {
            vm = fmaxf(vm, __shfl_xor(vm, off));
            vs += __shfl_xor(vs, off);
        }
        if (quad == 0) { lmax[w][t * 16 + col16] = vm; lsum[w][t * 16 + col16] = vs; }
    }
    __syncthreads();
    if (threadIdx.x < 128) {
        int col = threadIdx.x;
        float m = lmax[0][col], s = lsum[0][col];
        #pragma unroll
        for (int q = 1; q < 4; q++) { m = fmaxf(m, lmax[q][col]); s += lsum[q][col]; }
        size_t o = (size_t)(c * 8 + pb) * 512 + o0 + col;
        pmax[o] = m; psum[o] = s;
    }
}

// ---------------- pool reduce over 8 chunks ----------------
__global__ void poolred_kernel(const float* __restrict__ pmax, const float* __restrict__ psum,
                               float* __restrict__ feat) {
    int n = blockIdx.x * 256 + threadIdx.x;   // 16*512
    int o = n & 511, cl = n >> 9;
    float m = -INFINITY, s = 0.f;
    #pragma unroll
    for (int c = 0; c < 8; c++) {
        size_t q = (size_t)(cl * 8 + c) * 512 + o;
        m = fmaxf(m, pmax[q]); s += psum[q];
    }
    feat[(size_t)cl * 1024 + o] = m;
    feat[(size_t)cl * 1024 + 512 + o] = s * (1.f / 1024.f);
}

// ---------------- final MLP: wave-per-output ----------------
__global__ void mlp1_kernel(const float* __restrict__ feat, const float* __restrict__ L1,
                            const float* __restrict__ s6, const float* __restrict__ b6,
                            float* __restrict__ z1) {
    int wid = (blockIdx.x * 256 + threadIdx.x) >> 6;   // 0..8191
    int lane = threadIdx.x & 63;
    int o = wid & 511, b = wid >> 9;
    const float* f = feat + (size_t)b * 1024;
    const float* w = L1 + (size_t)o * 1024;
    float acc = 0.f;
    #pragma unroll
    for (int i = 0; i < 16; i++) acc = fmaf(f[i * 64 + lane], w[i * 64 + lane], acc);
    #pragma unroll
    for (int off = 32; off; off >>= 1) acc += __shfl_xor(acc, off);
    if (lane == 0) z1[wid] = lrelu(acc * s6[o] + b6[o]);
}

__global__ void mlp2_kernel(const float* __restrict__ z1, const float* __restrict__ L2,
                            const float* __restrict__ bl2,
                            const float* __restrict__ s7, const float* __restrict__ b7,
                            float* __restrict__ z2) {
    int wid = (blockIdx.x * 256 + threadIdx.x) >> 6;   // 0..4095
    int lane = threadIdx.x & 63;
    int o = wid & 255, b = wid >> 8;
    const float* f = z1 + (size_t)b * 512;
    const float* w = L2 + (size_t)o * 512;
    float acc = 0.f;
    #pragma unroll
    for (int i = 0; i < 8; i++) acc = fmaf(f[i * 64 + lane], w[i * 64 + lane], acc);
    #pragma unroll
    for (int off = 32; off; off >>= 1) acc += __shfl_xor(acc, off);
    if (lane == 0) z2[wid] = lrelu((acc + bl2[o]) * s7[o] + b7[o]);
}

__global__ void mlp3_kernel(const float* __restrict__ z2, const float* __restrict__ L3,
                            const float* __restrict__ bl3, float* __restrict__ out) {
    __shared__ float red[256];
    int t = threadIdx.x;
    int b = t >> 4, q = t & 15;
    float acc = 0.f;
    for (int c = q * 16; c < q * 16 + 16; c++) acc = fmaf(z2[(size_t)b * 256 + c], L3[c], acc);
    red[t] = acc;
    __syncthreads();
    if (q == 0) {
        float s = 0.f;
        #pragma unroll
        for (int i = 0; i < 16; i++) s += red[b * 16 + i];
        s += bl3[0];
        out[b] = 1.f / (1.f + expf(-s));
    }
}

extern "C" void kernel_launch(void* const* d_in, const int* in_sizes, int n_in,
                              void* d_out, int out_size, void* d_ws, size_t ws_size,
                              hipStream_t stream) {
    const float* features = (const float*)d_in[0];
    const int*   clusters = (const int*)d_in[1];
    const float* W1 = (const float*)d_in[2];
    const float* s1 = (const float*)d_in[3];
    const float* b1 = (const float*)d_in[4];
    const float* W2 = (const float*)d_in[5];
    const float* s2 = (const float*)d_in[6];
    const float* b2 = (const float*)d_in[7];
    const float* W3 = (const float*)d_in[8];
    const float* s3 = (const float*)d_in[9];
    const float* b3 = (const float*)d_in[10];
    const float* W4 = (const float*)d_in[11];
    const float* s4 = (const float*)d_in[12];
    const float* b4 = (const float*)d_in[13];
    const float* W5 = (const float*)d_in[14];
    const float* s5 = (const float*)d_in[15];
    const float* b5 = (const float*)d_in[16];
    const float* L1 = (const float*)d_in[17];
    const float* s6 = (const float*)d_in[18];
    const float* b6 = (const float*)d_in[19];
    const float* L2 = (const float*)d_in[20];
    const float* bl2 = (const float*)d_in[21];
    const float* s7 = (const float*)d_in[22];
    const float* b7 = (const float*)d_in[23];
    const float* L3 = (const float*)d_in[24];
    const float* bl3 = (const float*)d_in[25];

    float* ws = (float*)d_ws;
    float* U   = ws;                                      // 4,194,304 floats (max O=256)
    float* V   = U + 4194304;                             // 4,194,304
    _Float16* xcf16 = (_Float16*)(V + 4194304);           // 8,388,608 halfs (tiled K=512)
    _Float16* w5f16 = xcf16 + 8388608;                    // 262,144 halfs (tiled K=512)
    _Float16* hf16  = w5f16 + 262144;                     // 2,097,152 halfs (tiled, K=C)
    _Float16* wnA   = hf16 + 2097152;                     // 4 x 32,768 halfs
    _Float16* wvA   = wnA + 131072;                       // 4 x 32,768 halfs
    int*   idx  = (int*)(wvA + 131072);                   // 327,680 ints
    float* sqp  = (float*)(idx + 327680);                 // 32,768 (2 partials/row)
    float* pmax = sqp + 32768;                            // 131,072 (65,536 used)
    float* psum = pmax + 131072;                          // 131,072 (65,536 used)
    float* feat = psum + 131072;                          // 16,384
    float* z1   = feat + 16384;                           // 8,192
    float* z2   = z1 + 8192;                              // 4,096

    _Float16* wn[4] = { wnA, wnA + 32768, wnA + 65536, wnA + 98304 };
    _Float16* wv[4] = { wvA, wvA + 32768, wvA + 65536, wvA + 98304 };

    gather_kernel<<<2048, 256, 0, stream>>>((const float4*)features, clusters,
                                            (f16x4*)hf16, sqp);
    prep_kernel<<<308, 256, 0, stream>>>(W5, (f16x4*)w5f16,
                                         W1, (f16x4*)wn[0], (f16x4*)wv[0],
                                         W2, (f16x4*)wn[1], (f16x4*)wv[1],
                                         W3, (f16x4*)wn[2], (f16x4*)wv[2],
                                         W4, (f16x4*)wn[3], (f16x4*)wv[3]);

    auto stage = [&](int si, int C, int O, int lgO,
                     const float* sc, const float* bi,
                     int co, _Float16* hnext) {
        if (C == 128)
            grampk_kernel<128><<<1024, 1024, 0, stream>>>(hf16, sqp, idx);
        else
            grampk_kernel<64><<<1024, 1024, 0, stream>>>(hf16, sqp, idx);
        if (C == 128)
            uv_mfma_kernel<128><<<(O >> 6) * 256, 256, 0, stream>>>(hf16, lgO, wn[si], wv[si], U, V);
        else
            uv_mfma_kernel<64><<<(O >> 6) * 256, 256, 0, stream>>>(hf16, lgO, wn[si], wv[si], U, V);
        agg_kernel<<<(NCL * PPTS * O) / 256, 256, 0, stream>>>(U, V, idx, lgO, sc, bi,
                                                               hnext, xcf16, co, sqp);
    };

    stage(0, 128,  64, 6, s1, b1, 0,   hf16);
    stage(1,  64,  64, 6, s2, b2, 64,  hf16);
    stage(2,  64, 128, 7, s3, b3, 128, hf16);
    stage(3, 128, 256, 8, s4, b4, 256, (_Float16*)nullptr);

    conv5pool_kernel<<<512, 256, 0, stream>>>(xcf16, w5f16, s5, b5, pmax, psum);
    poolred_kernel<<<32, 256, 0, stream>>>(pmax, psum, feat);
    mlp1_kernel<<<2048, 256, 0, stream>>>(feat, L1, s6, b6, z1);
    mlp2_kernel<<<1024, 256, 0, stream>>>(z1, L2, bl2, s7, b7, z2);
    mlp3_kernel<<<1, 256, 0, stream>>>(z2, L3, bl3, (float*)d_out);
}